// Round 3
// baseline (643.767 us; speedup 1.0000x reference)
//
#include <hip/hip_runtime.h>

typedef unsigned short u16;
typedef _Float16 f16x8 __attribute__((ext_vector_type(8)));
typedef u16 u16x8 __attribute__((ext_vector_type(8)));
typedef float f32x4 __attribute__((ext_vector_type(4)));

#define NTOK 16384
#define CCH 512

__device__ __forceinline__ float h2f(u16 u) {
  _Float16 h = *(_Float16*)&u; return (float)h;
}
__device__ __forceinline__ u16 f2h(float f) {
  _Float16 h = (_Float16)f; return *(u16*)&h;
}
__device__ __forceinline__ void split2(float v, u16& hi, u16& lo) {
  hi = f2h(v); lo = f2h(v - h2f(hi));
}

// ---------- K0: x (C,N) f32 -> xT_hi/xT_lo (N,C) f16 pair ----------
__global__ __launch_bounds__(256) void k0_transpose_split(
    const float* __restrict__ x, u16* __restrict__ xh, u16* __restrict__ xl) {
  __shared__ float ld[32][33];
  const int t = threadIdx.x;
  const int n0 = blockIdx.x * 32, c0 = blockIdx.y * 32;
#pragma unroll
  for (int j = 0; j < 4; ++j) {
    int idx = t + 256 * j; int cl = idx >> 5, nl = idx & 31;
    ld[cl][nl] = x[(long)(c0 + cl) * NTOK + n0 + nl];
  }
  __syncthreads();
#pragma unroll
  for (int j = 0; j < 4; ++j) {
    int idx = t + 256 * j; int nl = idx >> 5, cl = idx & 31;
    float v = ld[cl][nl];
    u16 hi, lo; split2(v, hi, lo);
    long o = (long)(n0 + nl) * CCH + c0 + cl;
    xh[o] = hi; xl[o] = lo;
  }
}

// ---------- K0b: w_qkv f32 -> whi/wlo ----------
__global__ __launch_bounds__(256) void k0_cvt_w(const float* __restrict__ a,
                                                u16* __restrict__ oh,
                                                u16* __restrict__ ol) {
  int i = blockIdx.x * 256 + threadIdx.x;
  const float4 v = ((const float4*)a)[i];
  u16 h0, l0, h1, l1, h2, l2, h3, l3;
  split2(v.x, h0, l0); split2(v.y, h1, l1);
  split2(v.z, h2, l2); split2(v.w, h3, l3);
  ((unsigned long long*)oh)[i] = (unsigned long long)h0 | ((unsigned long long)h1 << 16)
                               | ((unsigned long long)h2 << 32) | ((unsigned long long)h3 << 48);
  ((unsigned long long*)ol)[i] = (unsigned long long)l0 | ((unsigned long long)l1 << 16)
                               | ((unsigned long long)l2 << 32) | ((unsigned long long)l3 << 48);
}

__device__ __forceinline__ void storeC(u16* p, float v) { *p = f2h(v); }
__device__ __forceinline__ void storeC(float* p, float v) { *p = v; }

// ---------- single-precision GEMM: C[M,N] = A[M,K]*B[N,K]^T (+bias), K=512
template <typename OutT, bool BIAS_ROW>
__global__ __launch_bounds__(256) void gemm_bt(
    const u16* __restrict__ A, const u16* __restrict__ B, OutT* __restrict__ C,
    const float* __restrict__ bias, int ldc) {
  const int K = 512;
  __shared__ __align__(16) u16 lA[128 * 64];
  __shared__ __align__(16) u16 lB[128 * 64];
  const int t = threadIdx.x;
  const int lane = t & 63, w = t >> 6;
  const int wm = w & 1, wn = w >> 1;
  const int bm = blockIdx.y * 128, bn = blockIdx.x * 128;
  const f32x4 zero4 = {0.f, 0.f, 0.f, 0.f};
  f32x4 acc[4][4];
#pragma unroll
  for (int i = 0; i < 4; ++i)
#pragma unroll
    for (int j = 0; j < 4; ++j) acc[i][j] = zero4;

  for (int kt = 0; kt < K; kt += 64) {
    u16x8 ra[4], rb[4];
#pragma unroll
    for (int j = 0; j < 4; ++j) {
      int idx = t + 256 * j;
      int row = idx >> 3, ko = (idx & 7) << 3;
      ra[j] = *(const u16x8*)(A + (long)(bm + row) * K + kt + ko);
      rb[j] = *(const u16x8*)(B + (long)(bn + row) * K + kt + ko);
    }
    __syncthreads();
#pragma unroll
    for (int j = 0; j < 4; ++j) {
      int idx = t + 256 * j;
      int row = idx >> 3, ko = (idx & 7) << 3;
      *(u16x8*)(&lA[row * 64 + ko]) = ra[j];
      *(u16x8*)(&lB[row * 64 + ko]) = rb[j];
    }
    __syncthreads();
#pragma unroll
    for (int kk = 0; kk < 2; ++kk) {
      f16x8 af[4], bfr[4];
#pragma unroll
      for (int f = 0; f < 4; ++f) {
        af[f]  = *(const f16x8*)(&lA[(wm * 64 + f * 16 + (lane & 15)) * 64 + kk * 32 + (lane >> 4) * 8]);
        bfr[f] = *(const f16x8*)(&lB[(wn * 64 + f * 16 + (lane & 15)) * 64 + kk * 32 + (lane >> 4) * 8]);
      }
#pragma unroll
      for (int i = 0; i < 4; ++i)
#pragma unroll
        for (int jj = 0; jj < 4; ++jj)
          acc[i][jj] = __builtin_amdgcn_mfma_f32_16x16x32_f16(af[i], bfr[jj], acc[i][jj], 0, 0, 0);
    }
  }
#pragma unroll
  for (int i = 0; i < 4; ++i) {
    const int r0 = bm + wm * 64 + i * 16 + (lane >> 4) * 4;
#pragma unroll
    for (int jj = 0; jj < 4; ++jj) {
      const int c0 = bn + wn * 64 + jj * 16 + (lane & 15);
      const float bcol = BIAS_ROW ? 0.f : bias[c0];
#pragma unroll
      for (int r = 0; r < 4; ++r) {
        float v = acc[i][jj][r] + (BIAS_ROW ? bias[r0 + r] : bcol);
        storeC(&C[(long)(r0 + r) * ldc + c0], v);
      }
    }
  }
}

// ---------- split GEMM: C = (Ah+Al)*(Bh+Bl)^T (+bias col), out hi/lo f16
__global__ __launch_bounds__(256) void gemm_split(
    const u16* __restrict__ Ah, const u16* __restrict__ Al,
    const u16* __restrict__ Bh, const u16* __restrict__ Bl,
    u16* __restrict__ Chi, u16* __restrict__ Clo,
    const float* __restrict__ bias, int ldc) {
  const int K = 512;
  __shared__ __align__(16) u16 lAh[128 * 64];
  __shared__ __align__(16) u16 lAl[128 * 64];
  __shared__ __align__(16) u16 lBh[128 * 64];
  __shared__ __align__(16) u16 lBl[128 * 64];
  const int t = threadIdx.x;
  const int lane = t & 63, w = t >> 6;
  const int wm = w & 1, wn = w >> 1;
  const int bm = blockIdx.y * 128, bn = blockIdx.x * 128;
  const f32x4 zero4 = {0.f, 0.f, 0.f, 0.f};
  f32x4 acc[4][4];
#pragma unroll
  for (int i = 0; i < 4; ++i)
#pragma unroll
    for (int j = 0; j < 4; ++j) acc[i][j] = zero4;

  for (int kt = 0; kt < K; kt += 64) {
    u16x8 rah[4], ral[4], rbh[4], rbl[4];
#pragma unroll
    for (int j = 0; j < 4; ++j) {
      int idx = t + 256 * j;
      int row = idx >> 3, ko = (idx & 7) << 3;
      rah[j] = *(const u16x8*)(Ah + (long)(bm + row) * K + kt + ko);
      ral[j] = *(const u16x8*)(Al + (long)(bm + row) * K + kt + ko);
      rbh[j] = *(const u16x8*)(Bh + (long)(bn + row) * K + kt + ko);
      rbl[j] = *(const u16x8*)(Bl + (long)(bn + row) * K + kt + ko);
    }
    __syncthreads();
#pragma unroll
    for (int j = 0; j < 4; ++j) {
      int idx = t + 256 * j;
      int row = idx >> 3, ko = (idx & 7) << 3;
      *(u16x8*)(&lAh[row * 64 + ko]) = rah[j];
      *(u16x8*)(&lAl[row * 64 + ko]) = ral[j];
      *(u16x8*)(&lBh[row * 64 + ko]) = rbh[j];
      *(u16x8*)(&lBl[row * 64 + ko]) = rbl[j];
    }
    __syncthreads();
#pragma unroll
    for (int kk = 0; kk < 2; ++kk) {
      f16x8 afh[4], afl[4], bfh[4], bfl[4];
#pragma unroll
      for (int f = 0; f < 4; ++f) {
        int off = (wm * 64 + f * 16 + (lane & 15)) * 64 + kk * 32 + (lane >> 4) * 8;
        int offb = (wn * 64 + f * 16 + (lane & 15)) * 64 + kk * 32 + (lane >> 4) * 8;
        afh[f] = *(const f16x8*)(&lAh[off]);
        afl[f] = *(const f16x8*)(&lAl[off]);
        bfh[f] = *(const f16x8*)(&lBh[offb]);
        bfl[f] = *(const f16x8*)(&lBl[offb]);
      }
#pragma unroll
      for (int i = 0; i < 4; ++i)
#pragma unroll
        for (int jj = 0; jj < 4; ++jj) {
          acc[i][jj] = __builtin_amdgcn_mfma_f32_16x16x32_f16(afh[i], bfh[jj], acc[i][jj], 0, 0, 0);
          acc[i][jj] = __builtin_amdgcn_mfma_f32_16x16x32_f16(afl[i], bfh[jj], acc[i][jj], 0, 0, 0);
          acc[i][jj] = __builtin_amdgcn_mfma_f32_16x16x32_f16(afh[i], bfl[jj], acc[i][jj], 0, 0, 0);
        }
    }
  }
#pragma unroll
  for (int i = 0; i < 4; ++i) {
    const int r0 = bm + wm * 64 + i * 16 + (lane >> 4) * 4;
#pragma unroll
    for (int jj = 0; jj < 4; ++jj) {
      const int c0 = bn + wn * 64 + jj * 16 + (lane & 15);
      const float bcol = bias[c0];
#pragma unroll
      for (int r = 0; r < 4; ++r) {
        float v = acc[i][jj][r] + bcol;
        u16 hi, lo; split2(v, hi, lo);
        long o = (long)(r0 + r) * ldc + c0;
        Chi[o] = hi; Clo[o] = lo;
      }
    }
  }
}

// ---------- K2qk: dw 3x3 in f32 on hi/lo input, out q/k hi/lo ch-major + sumsq
__global__ __launch_bounds__(256) void k2_qk(
    const u16* __restrict__ ph, const u16* __restrict__ pl,
    const float* __restrict__ wdw, const float* __restrict__ bdw,
    u16* __restrict__ qh, u16* __restrict__ ql,
    u16* __restrict__ kh, u16* __restrict__ kl, float* __restrict__ sumsq) {
  __shared__ __align__(16) char smem[3 * 66 * 64 * 4];
  float* st = (float*)smem;          // [dy*66+xi][c] f32 halo
  const int t = threadIdx.x;
  const int xc = blockIdx.x & 1, cc = blockIdx.x >> 1;  // cc: 0..15
  const int y = blockIdx.y;
  const int c0 = cc * 64;  // in [0,1024)
  for (int i = t; i < 1584; i += 256) {
    int l8 = i & 7, dyxi = i >> 3;
    int dy = dyxi / 66, xi = dyxi - dy * 66;
    int yy = y + dy - 1, xx = xc * 64 + xi - 1;
    float v[8];
    if (yy >= 0 && yy < 128 && xx >= 0 && xx < 128) {
      long o = (long)(yy * 128 + xx) * 1024 + c0 + l8 * 8;
      u16x8 hi8 = *(const u16x8*)(ph + o);
      u16x8 lo8 = *(const u16x8*)(pl + o);
#pragma unroll
      for (int e = 0; e < 8; ++e) v[e] = h2f(hi8[e]) + h2f(lo8[e]);
    } else {
#pragma unroll
      for (int e = 0; e < 8; ++e) v[e] = 0.f;
    }
#pragma unroll
    for (int e = 0; e < 8; ++e) st[dyxi * 64 + l8 * 8 + e] = v[e];
  }
  __syncthreads();
  const int ch2 = t & 31;
  const int xq = t >> 5;
  const int cga = c0 + 2 * ch2;
  float w0[9], w1[9];
#pragma unroll
  for (int i = 0; i < 9; ++i) { w0[i] = wdw[cga * 9 + i]; w1[i] = wdw[(cga + 1) * 9 + i]; }
  const float bi0 = bdw[cga], bi1 = bdw[cga + 1];
  float o0[8], o1[8];
#pragma unroll
  for (int m = 0; m < 8; ++m) {
    int xl = xq * 8 + m;
    float s0 = bi0, s1 = bi1;
#pragma unroll
    for (int dy = 0; dy < 3; ++dy)
#pragma unroll
      for (int dx = 0; dx < 3; ++dx) {
        const float2 v2 = *(const float2*)(&st[(dy * 66 + xl + dx) * 64 + 2 * ch2]);
        s0 += w0[dy * 3 + dx] * v2.x;
        s1 += w1[dy * 3 + dx] * v2.y;
      }
    o0[m] = s0; o1[m] = s1;
  }
  __syncthreads();  // done reading st; reuse smem for transpose buffers
  u16* trh = (u16*)smem;             // [64][65]
  u16* trl = trh + 64 * 65;
#pragma unroll
  for (int m = 0; m < 8; ++m) {
    int xl = xq * 8 + m;
    u16 h0, l0, h1, l1;
    split2(o0[m], h0, l0); split2(o1[m], h1, l1);
    trh[(2 * ch2) * 65 + xl] = h0; trl[(2 * ch2) * 65 + xl] = l0;
    trh[(2 * ch2 + 1) * 65 + xl] = h1; trl[(2 * ch2 + 1) * 65 + xl] = l1;
  }
  __syncthreads();
  const bool isq = (c0 < 512);
  u16* dh = isq ? qh : kh;
  u16* dl = isq ? ql : kl;
  const int crel0 = isq ? c0 : c0 - 512;
  const int nb = y * 128 + xc * 64;
  const int xl2 = t & 63, cq = t >> 6;
#pragma unroll
  for (int m2 = 0; m2 < 16; ++m2) {
    int c2 = cq + m2 * 4;
    u16 uh = trh[c2 * 65 + xl2];
    u16 ul = trl[c2 * 65 + xl2];
    float fv = h2f(uh) + h2f(ul);
    long o = (long)(crel0 + c2) * NTOK + nb + xl2;
    dh[o] = uh; dl[o] = ul;
    float s2 = fv * fv;
#pragma unroll
    for (int off = 32; off > 0; off >>= 1) s2 += __shfl_xor(s2, off);
    if (xl2 == 0) atomicAdd(&sumsq[(isq ? 0 : 512) + crel0 + c2], s2);
  }
}

// ---------- K2v: dw 3x3 single precision for v, out token-major ----------
__global__ __launch_bounds__(256) void k2_v(
    const u16* __restrict__ vpre, const float* __restrict__ wdw,
    const float* __restrict__ bdw, u16* __restrict__ vtm) {
  __shared__ __align__(16) u16 st[3 * 66 * 64];
  const int t = threadIdx.x;
  const int xc = blockIdx.x & 1, cc = blockIdx.x >> 1;  // cc: 0..7
  const int y = blockIdx.y;
  const int c0 = cc * 64;  // in [0,512)
  for (int i = t; i < 1584; i += 256) {
    int l8 = i & 7, dyxi = i >> 3;
    int dy = dyxi / 66, xi = dyxi - dy * 66;
    int yy = y + dy - 1, xx = xc * 64 + xi - 1;
    u16x8 val = {0, 0, 0, 0, 0, 0, 0, 0};
    if (yy >= 0 && yy < 128 && xx >= 0 && xx < 128)
      val = *(const u16x8*)(vpre + (long)(yy * 128 + xx) * 512 + c0 + l8 * 8);
    *(u16x8*)(&st[dyxi * 64 + l8 * 8]) = val;
  }
  __syncthreads();
  const int ch2 = t & 31;
  const int xq = t >> 5;
  const int cga = 1024 + c0 + 2 * ch2;  // dw weights for v live at rows 1024..1535
  float w0[9], w1[9];
#pragma unroll
  for (int i = 0; i < 9; ++i) { w0[i] = wdw[cga * 9 + i]; w1[i] = wdw[(cga + 1) * 9 + i]; }
  const float bi0 = bdw[cga], bi1 = bdw[cga + 1];
  const int nb = y * 128 + xc * 64;
#pragma unroll
  for (int m = 0; m < 8; ++m) {
    int xl = xq * 8 + m;
    float s0 = bi0, s1 = bi1;
#pragma unroll
    for (int dy = 0; dy < 3; ++dy)
#pragma unroll
      for (int dx = 0; dx < 3; ++dx) {
        unsigned int v2 = *(const unsigned int*)(&st[(dy * 66 + xl + dx) * 64 + 2 * ch2]);
        s0 += w0[dy * 3 + dx] * h2f((u16)(v2 & 0xffffu));
        s1 += w1[dy * 3 + dx] * h2f((u16)(v2 >> 16));
      }
    unsigned int pack = (unsigned int)f2h(s0) | ((unsigned int)f2h(s1) << 16);
    *(unsigned int*)(vtm + (long)(nb + xq * 8 + m) * 512 + c0 + 2 * ch2) = pack;
  }
}

// ---------- K3: att_raw[h] += q_h * k_h^T, split precision ----------
__global__ __launch_bounds__(256) void k3_qk_split(
    const u16* __restrict__ qh, const u16* __restrict__ ql,
    const u16* __restrict__ kh, const u16* __restrict__ kl,
    float* __restrict__ att_raw) {
  __shared__ __align__(16) u16 lqh[64 * 128];
  __shared__ __align__(16) u16 lql[64 * 128];
  __shared__ __align__(16) u16 lkh[64 * 128];
  __shared__ __align__(16) u16 lkl[64 * 128];
  const int t = threadIdx.x, lane = t & 63, w = t >> 6;
  const int h = blockIdx.y;
  const int n0b = blockIdx.x * 512;
  const u16* qhb = qh + (long)(h * 64) * NTOK;
  const u16* qlb = ql + (long)(h * 64) * NTOK;
  const u16* khb = kh + (long)(h * 64) * NTOK;
  const u16* klb = kl + (long)(h * 64) * NTOK;
  const f32x4 zero4 = {0.f, 0.f, 0.f, 0.f};
  f32x4 acc[4] = {zero4, zero4, zero4, zero4};
  for (int ch = 0; ch < 4; ++ch) {
    const int n0 = n0b + ch * 128;
    u16x8 r0[4], r1[4], r2[4], r3[4];
#pragma unroll
    for (int j = 0; j < 4; ++j) {
      int idx = t + 256 * j;
      int row = idx >> 4, ko = (idx & 15) << 3;
      long o = (long)row * NTOK + n0 + ko;
      r0[j] = *(const u16x8*)(qhb + o);
      r1[j] = *(const u16x8*)(qlb + o);
      r2[j] = *(const u16x8*)(khb + o);
      r3[j] = *(const u16x8*)(klb + o);
    }
    __syncthreads();
#pragma unroll
    for (int j = 0; j < 4; ++j) {
      int idx = t + 256 * j;
      int row = idx >> 4, ko = (idx & 15) << 3;
      *(u16x8*)(&lqh[row * 128 + ko]) = r0[j];
      *(u16x8*)(&lql[row * 128 + ko]) = r1[j];
      *(u16x8*)(&lkh[row * 128 + ko]) = r2[j];
      *(u16x8*)(&lkl[row * 128 + ko]) = r3[j];
    }
    __syncthreads();
#pragma unroll
    for (int kk = 0; kk < 4; ++kk) {
      int offb = (w * 16 + (lane & 15)) * 128 + kk * 32 + (lane >> 4) * 8;
      f16x8 bfh = *(const f16x8*)(&lkh[offb]);
      f16x8 bfl = *(const f16x8*)(&lkl[offb]);
#pragma unroll
      for (int f = 0; f < 4; ++f) {
        int offa = (f * 16 + (lane & 15)) * 128 + kk * 32 + (lane >> 4) * 8;
        f16x8 afh = *(const f16x8*)(&lqh[offa]);
        f16x8 afl = *(const f16x8*)(&lql[offa]);
        acc[f] = __builtin_amdgcn_mfma_f32_16x16x32_f16(afh, bfh, acc[f], 0, 0, 0);
        acc[f] = __builtin_amdgcn_mfma_f32_16x16x32_f16(afl, bfh, acc[f], 0, 0, 0);
        acc[f] = __builtin_amdgcn_mfma_f32_16x16x32_f16(afh, bfl, acc[f], 0, 0, 0);
      }
    }
  }
  float* dst = att_raw + h * 64 * 64;
#pragma unroll
  for (int f = 0; f < 4; ++f) {
    int rr = f * 16 + (lane >> 4) * 4;
    int col = w * 16 + (lane & 15);
#pragma unroll
    for (int r = 0; r < 4; ++r) atomicAdd(&dst[(rr + r) * 64 + col], acc[f][r]);
  }
}

// ---------- K4: normalize, exact top-42 threshold, softmax ----------
__global__ __launch_bounds__(256) void k4_sm(const float* __restrict__ att_raw,
                                             const float* __restrict__ sumsq,
                                             const float* __restrict__ scale_p,
                                             float* __restrict__ att) {
  const int t = threadIdx.x, lane = t & 63, w = t >> 6;
  const int row = blockIdx.x * 4 + w;  // 0..511
  const int hi = row >> 6, i = row & 63;
  const float scale = scale_p[0];
  const float nq = fmaxf(sqrtf(sumsq[hi * 64 + i]), 1e-12f);
  const float nk = fmaxf(sqrtf(sumsq[512 + hi * 64 + lane]), 1e-12f);
  float v = att_raw[(long)row * 64 + lane] * scale / (nq * nk);
  int cnt = 0;
  for (int m = 0; m < 64; ++m) {
    float vm = __shfl(v, m);
    cnt += (vm > v || (vm == v && m < lane)) ? 1 : 0;
  }
  unsigned long long ball = __ballot(cnt == 41);
  float thresh = __shfl(v, (int)__builtin_ctzll(ball));
  bool keep = v >= thresh;
  float mx = v;
#pragma unroll
  for (int o = 32; o > 0; o >>= 1) mx = fmaxf(mx, __shfl_xor(mx, o));
  float e = keep ? __expf(v - mx) : 0.f;
  float s = e;
#pragma unroll
  for (int o = 32; o > 0; o >>= 1) s += __shfl_xor(s, o);
  att[(long)row * 64 + lane] = e / s;
}

// ---------- K4b: M[c,h*64+j] = sum_i w_proj[c,h*64+i]*att[h,i,j] ----------
__global__ __launch_bounds__(256) void k4b_m(const float* __restrict__ att,
                                             const float* __restrict__ wproj,
                                             u16* __restrict__ Mb) {
  __shared__ float wl[64][64];
  __shared__ float al[64][64];
  const int t = threadIdx.x;
  const int cb = blockIdx.x, h = blockIdx.y;
  const int c0 = cb * 64;
#pragma unroll
  for (int j = 0; j < 16; ++j) {
    int idx = t + 256 * j;
    int r = idx >> 6, cix = idx & 63;
    wl[r][cix] = wproj[(long)(c0 + r) * 512 + h * 64 + cix];
    al[r][cix] = att[(h * 64 + r) * 64 + cix];
  }
  __syncthreads();
  const int jd = t & 63, cq = t >> 6;
#pragma unroll
  for (int m = 0; m < 16; ++m) {
    int cr = cq * 16 + m;
    float s = 0.f;
#pragma unroll
    for (int i2 = 0; i2 < 64; ++i2) s += wl[cr][i2] * al[i2][jd];
    Mb[(c0 + cr) * 512 + h * 64 + jd] = f2h(s);
  }
}

extern "C" void kernel_launch(void* const* d_in, const int* in_sizes, int n_in,
                              void* d_out, int out_size, void* d_ws, size_t ws_size,
                              hipStream_t stream) {
  (void)in_sizes; (void)n_in; (void)out_size; (void)ws_size;
  const float* x      = (const float*)d_in[0];
  const float* w_qkv  = (const float*)d_in[1];
  const float* b_qkv  = (const float*)d_in[2];
  const float* w_dw   = (const float*)d_in[3];
  const float* b_dw   = (const float*)d_in[4];
  const float* scale  = (const float*)d_in[5];
  const float* w_proj = (const float*)d_in[6];
  const float* b_proj = (const float*)d_in[7];
  float* out = (float*)d_out;
  char* ws = (char*)d_ws;

  // per-batch workspace (reused for b=0,1), peak ~172 MB
  u16* qkpre_hi = (u16*)(ws + 0L);            // (N,1024) f16  33554432
  u16* qkpre_lo = (u16*)(ws + 33554432L);     //               33554432
  u16* xT_hi    = (u16*)(ws + 67108864L);     // (N,512)       16777216  -> q_hi
  u16* xT_lo    = (u16*)(ws + 83886080L);     //               16777216  -> q_lo
  u16* k_hi     = (u16*)(ws + 100663296L);    // (512,N)       16777216
  u16* k_lo     = (u16*)(ws + 117440512L);    //               16777216
  u16* vpre     = (u16*)(ws + 134217728L);    // (N,512)       16777216
  u16* vtm      = (u16*)(ws + 150994944L);    // (N,512)       16777216
  u16* whi      = (u16*)(ws + 167772160L);    // (1536,512)    1572864
  u16* wlo      = (u16*)(ws + 169345024L);    //               1572864
  float* sumsq  = (float*)(ws + 170917888L);  // 1024 f32      4096
  float* att_raw= (float*)(ws + 170921984L);  // 8*64*64 f32   131072
  float* att    = (float*)(ws + 171053056L);  //               131072
  u16* Mb       = (u16*)(ws + 171184128L);    // (512,512)     524288
  u16* q_hi = xT_hi;  // alias: xT dead after the two GEMM1 passes
  u16* q_lo = xT_lo;

  k0_cvt_w<<<dim3(768), 256, 0, stream>>>(w_qkv, whi, wlo);

  for (int b = 0; b < 2; ++b) {
    const float* xb = x + (long)b * CCH * NTOK;
    float* outb = out + (long)b * CCH * NTOK;

    hipMemsetAsync(sumsq, 0, 4096 + 131072, stream);
    k0_transpose_split<<<dim3(512, 16, 1), 256, 0, stream>>>(xb, xT_hi, xT_lo);
    // q,k channels: split GEMM -> qkpre hi/lo (N,1024)
    gemm_split<<<dim3(8, 128, 1), 256, 0, stream>>>(
        xT_hi, xT_lo, whi, wlo, qkpre_hi, qkpre_lo, b_qkv, 1024);
    // v channels: single GEMM -> vpre (N,512)
    gemm_bt<u16, false><<<dim3(4, 128, 1), 256, 0, stream>>>(
        xT_hi, whi + (long)1024 * 512, vpre, b_qkv + 1024, 512);
    // depthwise: q/k (f32 path, xT buffers reused as q output)
    k2_qk<<<dim3(32, 128, 1), 256, 0, stream>>>(
        qkpre_hi, qkpre_lo, w_dw, b_dw, q_hi, q_lo, k_hi, k_lo, sumsq);
    k2_v<<<dim3(16, 128, 1), 256, 0, stream>>>(vpre, w_dw, b_dw, vtm);
    // qk^T split
    k3_qk_split<<<dim3(32, 8, 1), 256, 0, stream>>>(q_hi, q_lo, k_hi, k_lo, att_raw);
    k4_sm<<<dim3(128), 256, 0, stream>>>(att_raw, sumsq, scale, att);
    k4b_m<<<dim3(8, 8, 1), 256, 0, stream>>>(att, w_proj, Mb);
    // out[c][n] = sum_d Mb[c][d] * vtm[n][d] + b_proj[c]
    gemm_bt<float, true><<<dim3(128, 4, 1), 256, 0, stream>>>(
        Mb, vtm, outb, b_proj, NTOK);
  }
}

// Round 4
// 506.912 us; speedup vs baseline: 1.2700x; 1.2700x over previous
//
#include <hip/hip_runtime.h>

typedef unsigned short u16;
typedef _Float16 f16x8 __attribute__((ext_vector_type(8)));
typedef u16 u16x8 __attribute__((ext_vector_type(8)));
typedef float f32x4 __attribute__((ext_vector_type(4)));

#define NTOK 16384
#define CCH 512

__device__ __forceinline__ float h2f(u16 u) {
  _Float16 h = *(_Float16*)&u; return (float)h;
}
__device__ __forceinline__ u16 f2h(float f) {
  _Float16 h = (_Float16)f; return *(u16*)&h;
}
__device__ __forceinline__ void split2(float v, u16& hi, u16& lo) {
  hi = f2h(v); lo = f2h(v - h2f(hi));
}

// ---------- K0: x (C,N) f32 -> xT_hi/xT_lo (N,C) f16 pair ----------
__global__ __launch_bounds__(256) void k0_transpose_split(
    const float* __restrict__ x, u16* __restrict__ xh, u16* __restrict__ xl) {
  __shared__ float ld[32][33];
  const int t = threadIdx.x;
  const int n0 = blockIdx.x * 32, c0 = blockIdx.y * 32;
#pragma unroll
  for (int j = 0; j < 4; ++j) {
    int idx = t + 256 * j; int cl = idx >> 5, nl = idx & 31;
    ld[cl][nl] = x[(long)(c0 + cl) * NTOK + n0 + nl];
  }
  __syncthreads();
#pragma unroll
  for (int j = 0; j < 4; ++j) {
    int idx = t + 256 * j; int nl = idx >> 5, cl = idx & 31;
    float v = ld[cl][nl];
    u16 hi, lo; split2(v, hi, lo);
    long o = (long)(n0 + nl) * CCH + c0 + cl;
    xh[o] = hi; xl[o] = lo;
  }
}

// ---------- K0b: w_qkv f32 -> whi/wlo ----------
__global__ __launch_bounds__(256) void k0_cvt_w(const float* __restrict__ a,
                                                u16* __restrict__ oh,
                                                u16* __restrict__ ol) {
  int i = blockIdx.x * 256 + threadIdx.x;
  const float4 v = ((const float4*)a)[i];
  u16 h0, l0, h1, l1, h2, l2, h3, l3;
  split2(v.x, h0, l0); split2(v.y, h1, l1);
  split2(v.z, h2, l2); split2(v.w, h3, l3);
  ((unsigned long long*)oh)[i] = (unsigned long long)h0 | ((unsigned long long)h1 << 16)
                               | ((unsigned long long)h2 << 32) | ((unsigned long long)h3 << 48);
  ((unsigned long long*)ol)[i] = (unsigned long long)l0 | ((unsigned long long)l1 << 16)
                               | ((unsigned long long)l2 << 32) | ((unsigned long long)l3 << 48);
}

__device__ __forceinline__ void storeC(u16* p, float v) { *p = f2h(v); }
__device__ __forceinline__ void storeC(float* p, float v) { *p = v; }

// ---------- single-precision GEMM: C[M,N] = A[M,K]*B[N,K]^T (+bias), K=512
template <typename OutT, bool BIAS_ROW>
__global__ __launch_bounds__(256) void gemm_bt(
    const u16* __restrict__ A, const u16* __restrict__ B, OutT* __restrict__ C,
    const float* __restrict__ bias, int ldc) {
  const int K = 512;
  __shared__ __align__(16) u16 lA[128 * 64];
  __shared__ __align__(16) u16 lB[128 * 64];
  const int t = threadIdx.x;
  const int lane = t & 63, w = t >> 6;
  const int wm = w & 1, wn = w >> 1;
  const int bm = blockIdx.y * 128, bn = blockIdx.x * 128;
  const f32x4 zero4 = {0.f, 0.f, 0.f, 0.f};
  f32x4 acc[4][4];
#pragma unroll
  for (int i = 0; i < 4; ++i)
#pragma unroll
    for (int j = 0; j < 4; ++j) acc[i][j] = zero4;

  for (int kt = 0; kt < K; kt += 64) {
    u16x8 ra[4], rb[4];
#pragma unroll
    for (int j = 0; j < 4; ++j) {
      int idx = t + 256 * j;
      int row = idx >> 3, ko = (idx & 7) << 3;
      ra[j] = *(const u16x8*)(A + (long)(bm + row) * K + kt + ko);
      rb[j] = *(const u16x8*)(B + (long)(bn + row) * K + kt + ko);
    }
    __syncthreads();
#pragma unroll
    for (int j = 0; j < 4; ++j) {
      int idx = t + 256 * j;
      int row = idx >> 3, ko = (idx & 7) << 3;
      *(u16x8*)(&lA[row * 64 + ko]) = ra[j];
      *(u16x8*)(&lB[row * 64 + ko]) = rb[j];
    }
    __syncthreads();
#pragma unroll
    for (int kk = 0; kk < 2; ++kk) {
      f16x8 af[4], bfr[4];
#pragma unroll
      for (int f = 0; f < 4; ++f) {
        af[f]  = *(const f16x8*)(&lA[(wm * 64 + f * 16 + (lane & 15)) * 64 + kk * 32 + (lane >> 4) * 8]);
        bfr[f] = *(const f16x8*)(&lB[(wn * 64 + f * 16 + (lane & 15)) * 64 + kk * 32 + (lane >> 4) * 8]);
      }
#pragma unroll
      for (int i = 0; i < 4; ++i)
#pragma unroll
        for (int jj = 0; jj < 4; ++jj)
          acc[i][jj] = __builtin_amdgcn_mfma_f32_16x16x32_f16(af[i], bfr[jj], acc[i][jj], 0, 0, 0);
    }
  }
#pragma unroll
  for (int i = 0; i < 4; ++i) {
    const int r0 = bm + wm * 64 + i * 16 + (lane >> 4) * 4;
#pragma unroll
    for (int jj = 0; jj < 4; ++jj) {
      const int c0 = bn + wn * 64 + jj * 16 + (lane & 15);
      const float bcol = BIAS_ROW ? 0.f : bias[c0];
#pragma unroll
      for (int r = 0; r < 4; ++r) {
        float v = acc[i][jj][r] + (BIAS_ROW ? bias[r0 + r] : bcol);
        storeC(&C[(long)(r0 + r) * ldc + c0], v);
      }
    }
  }
}

// ---------- split GEMM: C[M,N] f32 = (Ah+Al)[M,K]*(Bh+Bl)[N,K]^T + bias[row]
// out channel-major f32 (ldc = N tokens)
__global__ __launch_bounds__(256) void gemm_split(
    const u16* __restrict__ Ah, const u16* __restrict__ Al,
    const u16* __restrict__ Bh, const u16* __restrict__ Bl,
    float* __restrict__ C, const float* __restrict__ bias, int ldc) {
  const int K = 512;
  __shared__ __align__(16) u16 lAh[128 * 64];
  __shared__ __align__(16) u16 lAl[128 * 64];
  __shared__ __align__(16) u16 lBh[128 * 64];
  __shared__ __align__(16) u16 lBl[128 * 64];
  const int t = threadIdx.x;
  const int lane = t & 63, w = t >> 6;
  const int wm = w & 1, wn = w >> 1;
  const int bm = blockIdx.y * 128, bn = blockIdx.x * 128;
  const f32x4 zero4 = {0.f, 0.f, 0.f, 0.f};
  f32x4 acc[4][4];
#pragma unroll
  for (int i = 0; i < 4; ++i)
#pragma unroll
    for (int j = 0; j < 4; ++j) acc[i][j] = zero4;

  for (int kt = 0; kt < K; kt += 64) {
    u16x8 rah[4], ral[4], rbh[4], rbl[4];
#pragma unroll
    for (int j = 0; j < 4; ++j) {
      int idx = t + 256 * j;
      int row = idx >> 3, ko = (idx & 7) << 3;
      rah[j] = *(const u16x8*)(Ah + (long)(bm + row) * K + kt + ko);
      ral[j] = *(const u16x8*)(Al + (long)(bm + row) * K + kt + ko);
      rbh[j] = *(const u16x8*)(Bh + (long)(bn + row) * K + kt + ko);
      rbl[j] = *(const u16x8*)(Bl + (long)(bn + row) * K + kt + ko);
    }
    __syncthreads();
#pragma unroll
    for (int j = 0; j < 4; ++j) {
      int idx = t + 256 * j;
      int row = idx >> 3, ko = (idx & 7) << 3;
      *(u16x8*)(&lAh[row * 64 + ko]) = rah[j];
      *(u16x8*)(&lAl[row * 64 + ko]) = ral[j];
      *(u16x8*)(&lBh[row * 64 + ko]) = rbh[j];
      *(u16x8*)(&lBl[row * 64 + ko]) = rbl[j];
    }
    __syncthreads();
#pragma unroll
    for (int kk = 0; kk < 2; ++kk) {
      f16x8 afh[4], afl[4], bfh[4], bfl[4];
#pragma unroll
      for (int f = 0; f < 4; ++f) {
        int off = (wm * 64 + f * 16 + (lane & 15)) * 64 + kk * 32 + (lane >> 4) * 8;
        int offb = (wn * 64 + f * 16 + (lane & 15)) * 64 + kk * 32 + (lane >> 4) * 8;
        afh[f] = *(const f16x8*)(&lAh[off]);
        afl[f] = *(const f16x8*)(&lAl[off]);
        bfh[f] = *(const f16x8*)(&lBh[offb]);
        bfl[f] = *(const f16x8*)(&lBl[offb]);
      }
#pragma unroll
      for (int i = 0; i < 4; ++i)
#pragma unroll
        for (int jj = 0; jj < 4; ++jj) {
          acc[i][jj] = __builtin_amdgcn_mfma_f32_16x16x32_f16(afh[i], bfh[jj], acc[i][jj], 0, 0, 0);
          acc[i][jj] = __builtin_amdgcn_mfma_f32_16x16x32_f16(afl[i], bfh[jj], acc[i][jj], 0, 0, 0);
          acc[i][jj] = __builtin_amdgcn_mfma_f32_16x16x32_f16(afh[i], bfl[jj], acc[i][jj], 0, 0, 0);
        }
    }
  }
#pragma unroll
  for (int i = 0; i < 4; ++i) {
    const int r0 = bm + wm * 64 + i * 16 + (lane >> 4) * 4;
#pragma unroll
    for (int jj = 0; jj < 4; ++jj) {
      const int c0 = bn + wn * 64 + jj * 16 + (lane & 15);
#pragma unroll
      for (int r = 0; r < 4; ++r) {
        C[(long)(r0 + r) * ldc + c0] = acc[i][jj][r] + bias[r0 + r];
      }
    }
  }
}

// ---------- K2qk: channel-major dw 3x3 on f32 input, out q/k hi/lo + sumsq
// qkpre: (1024, 16384) f32; block = (strip s in 0..3, channel ch in 0..1023)
__global__ __launch_bounds__(256) void k2_qk(
    const float* __restrict__ qkpre,
    const float* __restrict__ wdw, const float* __restrict__ bdw,
    u16* __restrict__ qh, u16* __restrict__ ql,
    u16* __restrict__ kh, u16* __restrict__ kl, float* __restrict__ sumsq) {
  __shared__ float st[34 * 128];
  const int t = threadIdx.x;
  const int s = blockIdx.x;   // strip
  const int ch = blockIdx.y;  // channel
  const int y0 = s * 32;
  const float* src = qkpre + (long)ch * NTOK;
  for (int i = t; i < 1088; i += 256) {
    int r = i >> 5, seg = (i & 31) * 4;
    int gy = y0 - 1 + r;
    float4 v = {0.f, 0.f, 0.f, 0.f};
    if (gy >= 0 && gy < 128) v = *(const float4*)(src + gy * 128 + seg);
    *(float4*)(&st[r * 128 + seg]) = v;
  }
  float wv[9];
#pragma unroll
  for (int i = 0; i < 9; ++i) wv[i] = wdw[ch * 9 + i];
  const float bi = bdw[ch];
  __syncthreads();
  const int y = t >> 3, xg = t & 7, x16 = xg * 16;
  float r0[18], r1[18], r2[18];
#pragma unroll
  for (int k = 0; k < 4; ++k) {
    *(float4*)(&r0[1 + 4 * k]) = *(const float4*)(&st[(y + 0) * 128 + x16 + 4 * k]);
    *(float4*)(&r1[1 + 4 * k]) = *(const float4*)(&st[(y + 1) * 128 + x16 + 4 * k]);
    *(float4*)(&r2[1 + 4 * k]) = *(const float4*)(&st[(y + 2) * 128 + x16 + 4 * k]);
  }
  r0[0]  = (xg > 0) ? st[(y + 0) * 128 + x16 - 1] : 0.f;
  r1[0]  = (xg > 0) ? st[(y + 1) * 128 + x16 - 1] : 0.f;
  r2[0]  = (xg > 0) ? st[(y + 2) * 128 + x16 - 1] : 0.f;
  r0[17] = (xg < 7) ? st[(y + 0) * 128 + x16 + 16] : 0.f;
  r1[17] = (xg < 7) ? st[(y + 1) * 128 + x16 + 16] : 0.f;
  r2[17] = (xg < 7) ? st[(y + 2) * 128 + x16 + 16] : 0.f;
  u16 oh[16], ol[16];
  float ss = 0.f;
#pragma unroll
  for (int j = 0; j < 16; ++j) {
    float o = bi;
    o += wv[0] * r0[j] + wv[1] * r0[j + 1] + wv[2] * r0[j + 2];
    o += wv[3] * r1[j] + wv[4] * r1[j + 1] + wv[5] * r1[j + 2];
    o += wv[6] * r2[j] + wv[7] * r2[j + 1] + wv[8] * r2[j + 2];
    ss += o * o;
    split2(o, oh[j], ol[j]);
  }
  const bool isq = ch < 512;
  u16* dh = isq ? qh : kh;
  u16* dl = isq ? ql : kl;
  const long o = (long)(isq ? ch : ch - 512) * NTOK + (y0 + y) * 128 + x16;
  *(u16x8*)(dh + o)     = *(u16x8*)&oh[0];
  *(u16x8*)(dh + o + 8) = *(u16x8*)&oh[8];
  *(u16x8*)(dl + o)     = *(u16x8*)&ol[0];
  *(u16x8*)(dl + o + 8) = *(u16x8*)&ol[8];
#pragma unroll
  for (int off = 32; off > 0; off >>= 1) ss += __shfl_xor(ss, off);
  if ((t & 63) == 0) atomicAdd(&sumsq[ch], ss);
}

// ---------- K2v: dw 3x3 single precision for v, out token-major ----------
__global__ __launch_bounds__(256) void k2_v(
    const u16* __restrict__ vpre, const float* __restrict__ wdw,
    const float* __restrict__ bdw, u16* __restrict__ vtm) {
  __shared__ __align__(16) u16 st[3 * 66 * 64];
  const int t = threadIdx.x;
  const int xc = blockIdx.x & 1, cc = blockIdx.x >> 1;  // cc: 0..7
  const int y = blockIdx.y;
  const int c0 = cc * 64;  // in [0,512)
  for (int i = t; i < 1584; i += 256) {
    int l8 = i & 7, dyxi = i >> 3;
    int dy = dyxi / 66, xi = dyxi - dy * 66;
    int yy = y + dy - 1, xx = xc * 64 + xi - 1;
    u16x8 val = {0, 0, 0, 0, 0, 0, 0, 0};
    if (yy >= 0 && yy < 128 && xx >= 0 && xx < 128)
      val = *(const u16x8*)(vpre + (long)(yy * 128 + xx) * 512 + c0 + l8 * 8);
    *(u16x8*)(&st[dyxi * 64 + l8 * 8]) = val;
  }
  __syncthreads();
  const int ch2 = t & 31;
  const int xq = t >> 5;
  const int cga = 1024 + c0 + 2 * ch2;  // dw weights for v live at rows 1024..1535
  float w0[9], w1[9];
#pragma unroll
  for (int i = 0; i < 9; ++i) { w0[i] = wdw[cga * 9 + i]; w1[i] = wdw[(cga + 1) * 9 + i]; }
  const float bi0 = bdw[cga], bi1 = bdw[cga + 1];
  const int nb = y * 128 + xc * 64;
#pragma unroll
  for (int m = 0; m < 8; ++m) {
    int xl = xq * 8 + m;
    float s0 = bi0, s1 = bi1;
#pragma unroll
    for (int dy = 0; dy < 3; ++dy)
#pragma unroll
      for (int dx = 0; dx < 3; ++dx) {
        unsigned int v2 = *(const unsigned int*)(&st[(dy * 66 + xl + dx) * 64 + 2 * ch2]);
        s0 += w0[dy * 3 + dx] * h2f((u16)(v2 & 0xffffu));
        s1 += w1[dy * 3 + dx] * h2f((u16)(v2 >> 16));
      }
    unsigned int pack = (unsigned int)f2h(s0) | ((unsigned int)f2h(s1) << 16);
    *(unsigned int*)(vtm + (long)(nb + xq * 8 + m) * 512 + c0 + 2 * ch2) = pack;
  }
}

// ---------- K3: att_raw[h] += q_h * k_h^T, split precision ----------
__global__ __launch_bounds__(256) void k3_qk_split(
    const u16* __restrict__ qh, const u16* __restrict__ ql,
    const u16* __restrict__ kh, const u16* __restrict__ kl,
    float* __restrict__ att_raw) {
  __shared__ __align__(16) u16 lqh[64 * 128];
  __shared__ __align__(16) u16 lql[64 * 128];
  __shared__ __align__(16) u16 lkh[64 * 128];
  __shared__ __align__(16) u16 lkl[64 * 128];
  const int t = threadIdx.x, lane = t & 63, w = t >> 6;
  const int h = blockIdx.y;
  const int n0b = blockIdx.x * 512;
  const u16* qhb = qh + (long)(h * 64) * NTOK;
  const u16* qlb = ql + (long)(h * 64) * NTOK;
  const u16* khb = kh + (long)(h * 64) * NTOK;
  const u16* klb = kl + (long)(h * 64) * NTOK;
  const f32x4 zero4 = {0.f, 0.f, 0.f, 0.f};
  f32x4 acc[4] = {zero4, zero4, zero4, zero4};
  for (int ch = 0; ch < 4; ++ch) {
    const int n0 = n0b + ch * 128;
    u16x8 r0[4], r1[4], r2[4], r3[4];
#pragma unroll
    for (int j = 0; j < 4; ++j) {
      int idx = t + 256 * j;
      int row = idx >> 4, ko = (idx & 15) << 3;
      long o = (long)row * NTOK + n0 + ko;
      r0[j] = *(const u16x8*)(qhb + o);
      r1[j] = *(const u16x8*)(qlb + o);
      r2[j] = *(const u16x8*)(khb + o);
      r3[j] = *(const u16x8*)(klb + o);
    }
    __syncthreads();
#pragma unroll
    for (int j = 0; j < 4; ++j) {
      int idx = t + 256 * j;
      int row = idx >> 4, ko = (idx & 15) << 3;
      *(u16x8*)(&lqh[row * 128 + ko]) = r0[j];
      *(u16x8*)(&lql[row * 128 + ko]) = r1[j];
      *(u16x8*)(&lkh[row * 128 + ko]) = r2[j];
      *(u16x8*)(&lkl[row * 128 + ko]) = r3[j];
    }
    __syncthreads();
#pragma unroll
    for (int kk = 0; kk < 4; ++kk) {
      int offb = (w * 16 + (lane & 15)) * 128 + kk * 32 + (lane >> 4) * 8;
      f16x8 bfh = *(const f16x8*)(&lkh[offb]);
      f16x8 bfl = *(const f16x8*)(&lkl[offb]);
#pragma unroll
      for (int f = 0; f < 4; ++f) {
        int offa = (f * 16 + (lane & 15)) * 128 + kk * 32 + (lane >> 4) * 8;
        f16x8 afh = *(const f16x8*)(&lqh[offa]);
        f16x8 afl = *(const f16x8*)(&lql[offa]);
        acc[f] = __builtin_amdgcn_mfma_f32_16x16x32_f16(afh, bfh, acc[f], 0, 0, 0);
        acc[f] = __builtin_amdgcn_mfma_f32_16x16x32_f16(afl, bfh, acc[f], 0, 0, 0);
        acc[f] = __builtin_amdgcn_mfma_f32_16x16x32_f16(afh, bfl, acc[f], 0, 0, 0);
      }
    }
  }
  float* dst = att_raw + h * 64 * 64;
#pragma unroll
  for (int f = 0; f < 4; ++f) {
    int rr = f * 16 + (lane >> 4) * 4;
    int col = w * 16 + (lane & 15);
#pragma unroll
    for (int r = 0; r < 4; ++r) atomicAdd(&dst[(rr + r) * 64 + col], acc[f][r]);
  }
}

// ---------- K4: normalize, exact top-42 threshold, softmax ----------
__global__ __launch_bounds__(256) void k4_sm(const float* __restrict__ att_raw,
                                             const float* __restrict__ sumsq,
                                             const float* __restrict__ scale_p,
                                             float* __restrict__ att) {
  const int t = threadIdx.x, lane = t & 63, w = t >> 6;
  const int row = blockIdx.x * 4 + w;  // 0..511
  const int hi = row >> 6, i = row & 63;
  const float scale = scale_p[0];
  const float nq = fmaxf(sqrtf(sumsq[hi * 64 + i]), 1e-12f);
  const float nk = fmaxf(sqrtf(sumsq[512 + hi * 64 + lane]), 1e-12f);
  float v = att_raw[(long)row * 64 + lane] * scale / (nq * nk);
  int cnt = 0;
  for (int m = 0; m < 64; ++m) {
    float vm = __shfl(v, m);
    cnt += (vm > v || (vm == v && m < lane)) ? 1 : 0;
  }
  unsigned long long ball = __ballot(cnt == 41);
  float thresh = __shfl(v, (int)__builtin_ctzll(ball));
  bool keep = v >= thresh;
  float mx = v;
#pragma unroll
  for (int o = 32; o > 0; o >>= 1) mx = fmaxf(mx, __shfl_xor(mx, o));
  float e = keep ? __expf(v - mx) : 0.f;
  float s = e;
#pragma unroll
  for (int o = 32; o > 0; o >>= 1) s += __shfl_xor(s, o);
  att[(long)row * 64 + lane] = e / s;
}

// ---------- K4b: M[c,h*64+j] = sum_i w_proj[c,h*64+i]*att[h,i,j] ----------
__global__ __launch_bounds__(256) void k4b_m(const float* __restrict__ att,
                                             const float* __restrict__ wproj,
                                             u16* __restrict__ Mb) {
  __shared__ float wl[64][64];
  __shared__ float al[64][64];
  const int t = threadIdx.x;
  const int cb = blockIdx.x, h = blockIdx.y;
  const int c0 = cb * 64;
#pragma unroll
  for (int j = 0; j < 16; ++j) {
    int idx = t + 256 * j;
    int r = idx >> 6, cix = idx & 63;
    wl[r][cix] = wproj[(long)(c0 + r) * 512 + h * 64 + cix];
    al[r][cix] = att[(h * 64 + r) * 64 + cix];
  }
  __syncthreads();
  const int jd = t & 63, cq = t >> 6;
#pragma unroll
  for (int m = 0; m < 16; ++m) {
    int cr = cq * 16 + m;
    float s = 0.f;
#pragma unroll
    for (int i2 = 0; i2 < 64; ++i2) s += wl[cr][i2] * al[i2][jd];
    Mb[(c0 + cr) * 512 + h * 64 + jd] = f2h(s);
  }
}

extern "C" void kernel_launch(void* const* d_in, const int* in_sizes, int n_in,
                              void* d_out, int out_size, void* d_ws, size_t ws_size,
                              hipStream_t stream) {
  (void)in_sizes; (void)n_in; (void)out_size; (void)ws_size;
  const float* x      = (const float*)d_in[0];
  const float* w_qkv  = (const float*)d_in[1];
  const float* b_qkv  = (const float*)d_in[2];
  const float* w_dw   = (const float*)d_in[3];
  const float* b_dw   = (const float*)d_in[4];
  const float* scale  = (const float*)d_in[5];
  const float* w_proj = (const float*)d_in[6];
  const float* b_proj = (const float*)d_in[7];
  float* out = (float*)d_out;
  char* ws = (char*)d_ws;

  // per-batch workspace (reused for b=0,1), peak ~172 MB
  float* qkpre  = (float*)(ws + 0L);          // (1024,N) f32  67108864
  u16* xT_hi    = (u16*)(ws + 67108864L);     // (N,512)       16777216  -> q_hi
  u16* xT_lo    = (u16*)(ws + 83886080L);     //               16777216  -> q_lo
  u16* k_hi     = (u16*)(ws + 100663296L);    // (512,N)       16777216
  u16* k_lo     = (u16*)(ws + 117440512L);    //               16777216
  u16* vpre     = (u16*)(ws + 134217728L);    // (N,512)       16777216
  u16* vtm      = (u16*)(ws + 150994944L);    // (N,512)       16777216
  u16* whi      = (u16*)(ws + 167772160L);    // (1536,512)    1572864
  u16* wlo      = (u16*)(ws + 169345024L);    //               1572864
  float* sumsq  = (float*)(ws + 170917888L);  // 1024 f32      4096
  float* att_raw= (float*)(ws + 170921984L);  // 8*64*64 f32   131072
  float* att    = (float*)(ws + 171053056L);  //               131072
  u16* Mb       = (u16*)(ws + 171184128L);    // (512,512)     524288
  u16* q_hi = xT_hi;  // alias: xT dead after the two GEMM1 passes
  u16* q_lo = xT_lo;

  k0_cvt_w<<<dim3(768), 256, 0, stream>>>(w_qkv, whi, wlo);

  for (int b = 0; b < 2; ++b) {
    const float* xb = x + (long)b * CCH * NTOK;
    float* outb = out + (long)b * CCH * NTOK;

    hipMemsetAsync(sumsq, 0, 4096 + 131072, stream);
    k0_transpose_split<<<dim3(512, 16, 1), 256, 0, stream>>>(xb, xT_hi, xT_lo);
    // q,k channels: split GEMM -> qkpre f32 channel-major (1024, N)
    gemm_split<<<dim3(128, 8, 1), 256, 0, stream>>>(
        whi, wlo, xT_hi, xT_lo, qkpre, b_qkv, NTOK);
    // v channels: single GEMM -> vpre (N,512) token-major
    gemm_bt<u16, false><<<dim3(4, 128, 1), 256, 0, stream>>>(
        xT_hi, whi + (long)1024 * 512, vpre, b_qkv + 1024, 512);
    // depthwise q/k: channel-major strips (xT buffers reused as q output)
    k2_qk<<<dim3(4, 1024, 1), 256, 0, stream>>>(
        qkpre, w_dw, b_dw, q_hi, q_lo, k_hi, k_lo, sumsq);
    k2_v<<<dim3(16, 128, 1), 256, 0, stream>>>(vpre, w_dw, b_dw, vtm);
    // qk^T split
    k3_qk_split<<<dim3(32, 8, 1), 256, 0, stream>>>(q_hi, q_lo, k_hi, k_lo, att_raw);
    k4_sm<<<dim3(128), 256, 0, stream>>>(att_raw, sumsq, scale, att);
    k4b_m<<<dim3(8, 8, 1), 256, 0, stream>>>(att, w_proj, Mb);
    // out[c][n] = sum_d Mb[c][d] * vtm[n][d] + b_proj[c]
    gemm_bt<float, true><<<dim3(128, 4, 1), 256, 0, stream>>>(
        Mb, vtm, outb, b_proj, NTOK);
  }
}

// Round 5
// 476.704 us; speedup vs baseline: 1.3505x; 1.0634x over previous
//
#include <hip/hip_runtime.h>

typedef unsigned short u16;
typedef _Float16 f16x8 __attribute__((ext_vector_type(8)));
typedef u16 u16x8 __attribute__((ext_vector_type(8)));
typedef float f32x4 __attribute__((ext_vector_type(4)));

#define NTOK 16384
#define CCH 512

__device__ __forceinline__ float h2f(u16 u) {
  _Float16 h = *(_Float16*)&u; return (float)h;
}
__device__ __forceinline__ u16 f2h(float f) {
  _Float16 h = (_Float16)f; return *(u16*)&h;
}
__device__ __forceinline__ void split2(float v, u16& hi, u16& lo) {
  hi = f2h(v); lo = f2h(v - h2f(hi));
}
// LDS bank-conflict swizzle: XOR 16B-slot index with low 3 row bits (T2/G4).
__device__ __forceinline__ int swz(int row, int ko) { return ko ^ ((row & 7) << 3); }

// ---------- K0: x (C,N) f32 -> xT_hi/xT_lo (N,C) f16 pair ----------
__global__ __launch_bounds__(256) void k0_transpose_split(
    const float* __restrict__ x, u16* __restrict__ xh, u16* __restrict__ xl) {
  __shared__ float ld[32][33];
  const int t = threadIdx.x;
  const int n0 = blockIdx.x * 32, c0 = blockIdx.y * 32;
#pragma unroll
  for (int j = 0; j < 4; ++j) {
    int idx = t + 256 * j; int cl = idx >> 5, nl = idx & 31;
    ld[cl][nl] = x[(long)(c0 + cl) * NTOK + n0 + nl];
  }
  __syncthreads();
#pragma unroll
  for (int j = 0; j < 4; ++j) {
    int idx = t + 256 * j; int nl = idx >> 5, cl = idx & 31;
    float v = ld[cl][nl];
    u16 hi, lo; split2(v, hi, lo);
    long o = (long)(n0 + nl) * CCH + c0 + cl;
    xh[o] = hi; xl[o] = lo;
  }
}

// ---------- K0b: w_qkv f32 -> whi/wlo ----------
__global__ __launch_bounds__(256) void k0_cvt_w(const float* __restrict__ a,
                                                u16* __restrict__ oh,
                                                u16* __restrict__ ol) {
  int i = blockIdx.x * 256 + threadIdx.x;
  const float4 v = ((const float4*)a)[i];
  u16 h0, l0, h1, l1, h2, l2, h3, l3;
  split2(v.x, h0, l0); split2(v.y, h1, l1);
  split2(v.z, h2, l2); split2(v.w, h3, l3);
  ((unsigned long long*)oh)[i] = (unsigned long long)h0 | ((unsigned long long)h1 << 16)
                               | ((unsigned long long)h2 << 32) | ((unsigned long long)h3 << 48);
  ((unsigned long long*)ol)[i] = (unsigned long long)l0 | ((unsigned long long)l1 << 16)
                               | ((unsigned long long)l2 << 32) | ((unsigned long long)l3 << 48);
}

__device__ __forceinline__ void storeC(u16* p, float v) { *p = f2h(v); }
__device__ __forceinline__ void storeC(float* p, float v) { *p = v; }

// ---------- single-precision GEMM: C[M,N] = A[M,K]*B[N,K]^T (+bias), K=512
template <typename OutT, bool BIAS_ROW>
__global__ __launch_bounds__(256) void gemm_bt(
    const u16* __restrict__ A, const u16* __restrict__ B, OutT* __restrict__ C,
    const float* __restrict__ bias, int ldc) {
  const int K = 512;
  __shared__ __align__(16) u16 lA[128 * 64];
  __shared__ __align__(16) u16 lB[128 * 64];
  const int t = threadIdx.x;
  const int lane = t & 63, w = t >> 6;
  const int wm = w & 1, wn = w >> 1;
  const int bm = blockIdx.y * 128, bn = blockIdx.x * 128;
  const f32x4 zero4 = {0.f, 0.f, 0.f, 0.f};
  f32x4 acc[4][4];
#pragma unroll
  for (int i = 0; i < 4; ++i)
#pragma unroll
    for (int j = 0; j < 4; ++j) acc[i][j] = zero4;

  for (int kt = 0; kt < K; kt += 64) {
    u16x8 ra[4], rb[4];
#pragma unroll
    for (int j = 0; j < 4; ++j) {
      int idx = t + 256 * j;
      int row = idx >> 3, ko = (idx & 7) << 3;
      ra[j] = *(const u16x8*)(A + (long)(bm + row) * K + kt + ko);
      rb[j] = *(const u16x8*)(B + (long)(bn + row) * K + kt + ko);
    }
    __syncthreads();
#pragma unroll
    for (int j = 0; j < 4; ++j) {
      int idx = t + 256 * j;
      int row = idx >> 3, ko = (idx & 7) << 3;
      *(u16x8*)(&lA[row * 64 + swz(row, ko)]) = ra[j];
      *(u16x8*)(&lB[row * 64 + swz(row, ko)]) = rb[j];
    }
    __syncthreads();
#pragma unroll
    for (int kk = 0; kk < 2; ++kk) {
      f16x8 af[4], bfr[4];
#pragma unroll
      for (int f = 0; f < 4; ++f) {
        int ar = wm * 64 + f * 16 + (lane & 15);
        int br = wn * 64 + f * 16 + (lane & 15);
        int ko = kk * 32 + (lane >> 4) * 8;
        af[f]  = *(const f16x8*)(&lA[ar * 64 + swz(ar, ko)]);
        bfr[f] = *(const f16x8*)(&lB[br * 64 + swz(br, ko)]);
      }
#pragma unroll
      for (int i = 0; i < 4; ++i)
#pragma unroll
        for (int jj = 0; jj < 4; ++jj)
          acc[i][jj] = __builtin_amdgcn_mfma_f32_16x16x32_f16(af[i], bfr[jj], acc[i][jj], 0, 0, 0);
    }
  }
#pragma unroll
  for (int i = 0; i < 4; ++i) {
    const int r0 = bm + wm * 64 + i * 16 + (lane >> 4) * 4;
#pragma unroll
    for (int jj = 0; jj < 4; ++jj) {
      const int c0 = bn + wn * 64 + jj * 16 + (lane & 15);
      const float bcol = BIAS_ROW ? 0.f : bias[c0];
#pragma unroll
      for (int r = 0; r < 4; ++r) {
        float v = acc[i][jj][r] + (BIAS_ROW ? bias[r0 + r] : bcol);
        storeC(&C[(long)(r0 + r) * ldc + c0], v);
      }
    }
  }
}

// ---------- split GEMM: C[M,N] f32 = (Ah+Al)[M,K]*(Bh+Bl)[N,K]^T + bias[row]
// A-lo (weights, L2-resident) fragments loaded direct global->VGPR (no LDS).
// out channel-major f32 (ldc = N tokens)
__global__ __launch_bounds__(256) void gemm_split(
    const u16* __restrict__ Ah, const u16* __restrict__ Al,
    const u16* __restrict__ Bh, const u16* __restrict__ Bl,
    float* __restrict__ C, const float* __restrict__ bias, int ldc) {
  const int K = 512;
  __shared__ __align__(16) u16 lAh[128 * 64];
  __shared__ __align__(16) u16 lBh[128 * 64];
  __shared__ __align__(16) u16 lBl[128 * 64];
  const int t = threadIdx.x;
  const int lane = t & 63, w = t >> 6;
  const int wm = w & 1, wn = w >> 1;
  const int bm = blockIdx.y * 128, bn = blockIdx.x * 128;
  const f32x4 zero4 = {0.f, 0.f, 0.f, 0.f};
  f32x4 acc[4][4];
#pragma unroll
  for (int i = 0; i < 4; ++i)
#pragma unroll
    for (int j = 0; j < 4; ++j) acc[i][j] = zero4;

  // per-lane base for direct A-lo fragment loads
  const u16* Alp = Al + (long)(bm + wm * 64 + (lane & 15)) * K + ((lane >> 4) << 3);

  for (int kt = 0; kt < K; kt += 64) {
    u16x8 rah[4], rbh[4], rbl[4];
#pragma unroll
    for (int j = 0; j < 4; ++j) {
      int idx = t + 256 * j;
      int row = idx >> 3, ko = (idx & 7) << 3;
      rah[j] = *(const u16x8*)(Ah + (long)(bm + row) * K + kt + ko);
      rbh[j] = *(const u16x8*)(Bh + (long)(bn + row) * K + kt + ko);
      rbl[j] = *(const u16x8*)(Bl + (long)(bn + row) * K + kt + ko);
    }
    // direct A-lo fragments for this kt (L2-hit; overlaps with barriers)
    f16x8 afl[2][4];
#pragma unroll
    for (int kk = 0; kk < 2; ++kk)
#pragma unroll
      for (int f = 0; f < 4; ++f)
        afl[kk][f] = *(const f16x8*)(Alp + (long)(f * 16) * K + kt + kk * 32);
    __syncthreads();
#pragma unroll
    for (int j = 0; j < 4; ++j) {
      int idx = t + 256 * j;
      int row = idx >> 3, ko = (idx & 7) << 3;
      *(u16x8*)(&lAh[row * 64 + swz(row, ko)]) = rah[j];
      *(u16x8*)(&lBh[row * 64 + swz(row, ko)]) = rbh[j];
      *(u16x8*)(&lBl[row * 64 + swz(row, ko)]) = rbl[j];
    }
    __syncthreads();
#pragma unroll
    for (int kk = 0; kk < 2; ++kk) {
      f16x8 afh[4], bfh[4], bfl[4];
#pragma unroll
      for (int f = 0; f < 4; ++f) {
        int ar = wm * 64 + f * 16 + (lane & 15);
        int br = wn * 64 + f * 16 + (lane & 15);
        int ko = kk * 32 + (lane >> 4) * 8;
        afh[f] = *(const f16x8*)(&lAh[ar * 64 + swz(ar, ko)]);
        bfh[f] = *(const f16x8*)(&lBh[br * 64 + swz(br, ko)]);
        bfl[f] = *(const f16x8*)(&lBl[br * 64 + swz(br, ko)]);
      }
#pragma unroll
      for (int i = 0; i < 4; ++i)
#pragma unroll
        for (int jj = 0; jj < 4; ++jj) {
          acc[i][jj] = __builtin_amdgcn_mfma_f32_16x16x32_f16(afh[i], bfh[jj], acc[i][jj], 0, 0, 0);
          acc[i][jj] = __builtin_amdgcn_mfma_f32_16x16x32_f16(afl[kk][i], bfh[jj], acc[i][jj], 0, 0, 0);
          acc[i][jj] = __builtin_amdgcn_mfma_f32_16x16x32_f16(afh[i], bfl[jj], acc[i][jj], 0, 0, 0);
        }
    }
  }
#pragma unroll
  for (int i = 0; i < 4; ++i) {
    const int r0 = bm + wm * 64 + i * 16 + (lane >> 4) * 4;
#pragma unroll
    for (int jj = 0; jj < 4; ++jj) {
      const int c0 = bn + wn * 64 + jj * 16 + (lane & 15);
#pragma unroll
      for (int r = 0; r < 4; ++r) {
        C[(long)(r0 + r) * ldc + c0] = acc[i][jj][r] + bias[r0 + r];
      }
    }
  }
}

// ---------- K2qk: channel-major dw 3x3 on f32 input, out q/k hi/lo + sumsq
__global__ __launch_bounds__(256) void k2_qk(
    const float* __restrict__ qkpre,
    const float* __restrict__ wdw, const float* __restrict__ bdw,
    u16* __restrict__ qh, u16* __restrict__ ql,
    u16* __restrict__ kh, u16* __restrict__ kl, float* __restrict__ sumsq) {
  __shared__ float st[34 * 128];
  const int t = threadIdx.x;
  const int s = blockIdx.x;   // strip
  const int ch = blockIdx.y;  // channel
  const int y0 = s * 32;
  const float* src = qkpre + (long)ch * NTOK;
  for (int i = t; i < 1088; i += 256) {
    int r = i >> 5, seg = (i & 31) * 4;
    int gy = y0 - 1 + r;
    float4 v = {0.f, 0.f, 0.f, 0.f};
    if (gy >= 0 && gy < 128) v = *(const float4*)(src + gy * 128 + seg);
    *(float4*)(&st[r * 128 + seg]) = v;
  }
  float wv[9];
#pragma unroll
  for (int i = 0; i < 9; ++i) wv[i] = wdw[ch * 9 + i];
  const float bi = bdw[ch];
  __syncthreads();
  const int y = t >> 3, xg = t & 7, x16 = xg * 16;
  float r0[18], r1[18], r2[18];
#pragma unroll
  for (int k = 0; k < 4; ++k) {
    *(float4*)(&r0[1 + 4 * k]) = *(const float4*)(&st[(y + 0) * 128 + x16 + 4 * k]);
    *(float4*)(&r1[1 + 4 * k]) = *(const float4*)(&st[(y + 1) * 128 + x16 + 4 * k]);
    *(float4*)(&r2[1 + 4 * k]) = *(const float4*)(&st[(y + 2) * 128 + x16 + 4 * k]);
  }
  r0[0]  = (xg > 0) ? st[(y + 0) * 128 + x16 - 1] : 0.f;
  r1[0]  = (xg > 0) ? st[(y + 1) * 128 + x16 - 1] : 0.f;
  r2[0]  = (xg > 0) ? st[(y + 2) * 128 + x16 - 1] : 0.f;
  r0[17] = (xg < 7) ? st[(y + 0) * 128 + x16 + 16] : 0.f;
  r1[17] = (xg < 7) ? st[(y + 1) * 128 + x16 + 16] : 0.f;
  r2[17] = (xg < 7) ? st[(y + 2) * 128 + x16 + 16] : 0.f;
  u16 oh[16], ol[16];
  float ss = 0.f;
#pragma unroll
  for (int j = 0; j < 16; ++j) {
    float o = bi;
    o += wv[0] * r0[j] + wv[1] * r0[j + 1] + wv[2] * r0[j + 2];
    o += wv[3] * r1[j] + wv[4] * r1[j + 1] + wv[5] * r1[j + 2];
    o += wv[6] * r2[j] + wv[7] * r2[j + 1] + wv[8] * r2[j + 2];
    ss += o * o;
    split2(o, oh[j], ol[j]);
  }
  const bool isq = ch < 512;
  u16* dh = isq ? qh : kh;
  u16* dl = isq ? ql : kl;
  const long o = (long)(isq ? ch : ch - 512) * NTOK + (y0 + y) * 128 + x16;
  *(u16x8*)(dh + o)     = *(u16x8*)&oh[0];
  *(u16x8*)(dh + o + 8) = *(u16x8*)&oh[8];
  *(u16x8*)(dl + o)     = *(u16x8*)&ol[0];
  *(u16x8*)(dl + o + 8) = *(u16x8*)&ol[8];
#pragma unroll
  for (int off = 32; off > 0; off >>= 1) ss += __shfl_xor(ss, off);
  if ((t & 63) == 0) atomicAdd(&sumsq[ch], ss);
}

// ---------- K2v: dw 3x3 single precision for v, out token-major ----------
__global__ __launch_bounds__(256) void k2_v(
    const u16* __restrict__ vpre, const float* __restrict__ wdw,
    const float* __restrict__ bdw, u16* __restrict__ vtm) {
  __shared__ __align__(16) u16 st[3 * 66 * 64];
  const int t = threadIdx.x;
  const int xc = blockIdx.x & 1, cc = blockIdx.x >> 1;  // cc: 0..7
  const int y = blockIdx.y;
  const int c0 = cc * 64;  // in [0,512)
  for (int i = t; i < 1584; i += 256) {
    int l8 = i & 7, dyxi = i >> 3;
    int dy = dyxi / 66, xi = dyxi - dy * 66;
    int yy = y + dy - 1, xx = xc * 64 + xi - 1;
    u16x8 val = {0, 0, 0, 0, 0, 0, 0, 0};
    if (yy >= 0 && yy < 128 && xx >= 0 && xx < 128)
      val = *(const u16x8*)(vpre + (long)(yy * 128 + xx) * 512 + c0 + l8 * 8);
    *(u16x8*)(&st[dyxi * 64 + l8 * 8]) = val;
  }
  __syncthreads();
  const int ch2 = t & 31;
  const int xq = t >> 5;
  const int cga = 1024 + c0 + 2 * ch2;  // dw weights for v live at rows 1024..1535
  float w0[9], w1[9];
#pragma unroll
  for (int i = 0; i < 9; ++i) { w0[i] = wdw[cga * 9 + i]; w1[i] = wdw[(cga + 1) * 9 + i]; }
  const float bi0 = bdw[cga], bi1 = bdw[cga + 1];
  const int nb = y * 128 + xc * 64;
#pragma unroll
  for (int m = 0; m < 8; ++m) {
    int xl = xq * 8 + m;
    float s0 = bi0, s1 = bi1;
#pragma unroll
    for (int dy = 0; dy < 3; ++dy)
#pragma unroll
      for (int dx = 0; dx < 3; ++dx) {
        unsigned int v2 = *(const unsigned int*)(&st[(dy * 66 + xl + dx) * 64 + 2 * ch2]);
        s0 += w0[dy * 3 + dx] * h2f((u16)(v2 & 0xffffu));
        s1 += w1[dy * 3 + dx] * h2f((u16)(v2 >> 16));
      }
    unsigned int pack = (unsigned int)f2h(s0) | ((unsigned int)f2h(s1) << 16);
    *(unsigned int*)(vtm + (long)(nb + xq * 8 + m) * 512 + c0 + 2 * ch2) = pack;
  }
}

// ---------- K3: att_raw[h] += q_h * k_h^T, split precision ----------
__global__ __launch_bounds__(256) void k3_qk_split(
    const u16* __restrict__ qh, const u16* __restrict__ ql,
    const u16* __restrict__ kh, const u16* __restrict__ kl,
    float* __restrict__ att_raw) {
  __shared__ __align__(16) u16 lqh[64 * 128];
  __shared__ __align__(16) u16 lql[64 * 128];
  __shared__ __align__(16) u16 lkh[64 * 128];
  __shared__ __align__(16) u16 lkl[64 * 128];
  const int t = threadIdx.x, lane = t & 63, w = t >> 6;
  const int h = blockIdx.y;
  const int n0b = blockIdx.x * 512;
  const u16* qhb = qh + (long)(h * 64) * NTOK;
  const u16* qlb = ql + (long)(h * 64) * NTOK;
  const u16* khb = kh + (long)(h * 64) * NTOK;
  const u16* klb = kl + (long)(h * 64) * NTOK;
  const f32x4 zero4 = {0.f, 0.f, 0.f, 0.f};
  f32x4 acc[4] = {zero4, zero4, zero4, zero4};
  for (int ch = 0; ch < 4; ++ch) {
    const int n0 = n0b + ch * 128;
    u16x8 r0[4], r1[4], r2[4], r3[4];
#pragma unroll
    for (int j = 0; j < 4; ++j) {
      int idx = t + 256 * j;
      int row = idx >> 4, ko = (idx & 15) << 3;
      long o = (long)row * NTOK + n0 + ko;
      r0[j] = *(const u16x8*)(qhb + o);
      r1[j] = *(const u16x8*)(qlb + o);
      r2[j] = *(const u16x8*)(khb + o);
      r3[j] = *(const u16x8*)(klb + o);
    }
    __syncthreads();
#pragma unroll
    for (int j = 0; j < 4; ++j) {
      int idx = t + 256 * j;
      int row = idx >> 4, ko = (idx & 15) << 3;
      int sko = swz(row, ko);
      *(u16x8*)(&lqh[row * 128 + sko]) = r0[j];
      *(u16x8*)(&lql[row * 128 + sko]) = r1[j];
      *(u16x8*)(&lkh[row * 128 + sko]) = r2[j];
      *(u16x8*)(&lkl[row * 128 + sko]) = r3[j];
    }
    __syncthreads();
#pragma unroll
    for (int kk = 0; kk < 4; ++kk) {
      int br = w * 16 + (lane & 15);
      int ko = kk * 32 + (lane >> 4) * 8;
      f16x8 bfh = *(const f16x8*)(&lkh[br * 128 + swz(br, ko)]);
      f16x8 bfl = *(const f16x8*)(&lkl[br * 128 + swz(br, ko)]);
#pragma unroll
      for (int f = 0; f < 4; ++f) {
        int ar = f * 16 + (lane & 15);
        f16x8 afh = *(const f16x8*)(&lqh[ar * 128 + swz(ar, ko)]);
        f16x8 afl = *(const f16x8*)(&lql[ar * 128 + swz(ar, ko)]);
        acc[f] = __builtin_amdgcn_mfma_f32_16x16x32_f16(afh, bfh, acc[f], 0, 0, 0);
        acc[f] = __builtin_amdgcn_mfma_f32_16x16x32_f16(afl, bfh, acc[f], 0, 0, 0);
        acc[f] = __builtin_amdgcn_mfma_f32_16x16x32_f16(afh, bfl, acc[f], 0, 0, 0);
      }
    }
  }
  float* dst = att_raw + h * 64 * 64;
#pragma unroll
  for (int f = 0; f < 4; ++f) {
    int rr = f * 16 + (lane >> 4) * 4;
    int col = w * 16 + (lane & 15);
#pragma unroll
    for (int r = 0; r < 4; ++r) atomicAdd(&dst[(rr + r) * 64 + col], acc[f][r]);
  }
}

// ---------- K4: normalize, exact top-42 threshold, softmax ----------
__global__ __launch_bounds__(256) void k4_sm(const float* __restrict__ att_raw,
                                             const float* __restrict__ sumsq,
                                             const float* __restrict__ scale_p,
                                             float* __restrict__ att) {
  const int t = threadIdx.x, lane = t & 63, w = t >> 6;
  const int row = blockIdx.x * 4 + w;  // 0..511
  const int hi = row >> 6, i = row & 63;
  const float scale = scale_p[0];
  const float nq = fmaxf(sqrtf(sumsq[hi * 64 + i]), 1e-12f);
  const float nk = fmaxf(sqrtf(sumsq[512 + hi * 64 + lane]), 1e-12f);
  float v = att_raw[(long)row * 64 + lane] * scale / (nq * nk);
  int cnt = 0;
  for (int m = 0; m < 64; ++m) {
    float vm = __shfl(v, m);
    cnt += (vm > v || (vm == v && m < lane)) ? 1 : 0;
  }
  unsigned long long ball = __ballot(cnt == 41);
  float thresh = __shfl(v, (int)__builtin_ctzll(ball));
  bool keep = v >= thresh;
  float mx = v;
#pragma unroll
  for (int o = 32; o > 0; o >>= 1) mx = fmaxf(mx, __shfl_xor(mx, o));
  float e = keep ? __expf(v - mx) : 0.f;
  float s = e;
#pragma unroll
  for (int o = 32; o > 0; o >>= 1) s += __shfl_xor(s, o);
  att[(long)row * 64 + lane] = e / s;
}

// ---------- K4b: M[c,h*64+j] = sum_i w_proj[c,h*64+i]*att[h,i,j] ----------
__global__ __launch_bounds__(256) void k4b_m(const float* __restrict__ att,
                                             const float* __restrict__ wproj,
                                             u16* __restrict__ Mb) {
  __shared__ float wl[64][64];
  __shared__ float al[64][64];
  const int t = threadIdx.x;
  const int cb = blockIdx.x, h = blockIdx.y;
  const int c0 = cb * 64;
#pragma unroll
  for (int j = 0; j < 16; ++j) {
    int idx = t + 256 * j;
    int r = idx >> 6, cix = idx & 63;
    wl[r][cix] = wproj[(long)(c0 + r) * 512 + h * 64 + cix];
    al[r][cix] = att[(h * 64 + r) * 64 + cix];
  }
  __syncthreads();
  const int jd = t & 63, cq = t >> 6;
#pragma unroll
  for (int m = 0; m < 16; ++m) {
    int cr = cq * 16 + m;
    float s = 0.f;
#pragma unroll
    for (int i2 = 0; i2 < 64; ++i2) s += wl[cr][i2] * al[i2][jd];
    Mb[(c0 + cr) * 512 + h * 64 + jd] = f2h(s);
  }
}

extern "C" void kernel_launch(void* const* d_in, const int* in_sizes, int n_in,
                              void* d_out, int out_size, void* d_ws, size_t ws_size,
                              hipStream_t stream) {
  (void)in_sizes; (void)n_in; (void)out_size; (void)ws_size;
  const float* x      = (const float*)d_in[0];
  const float* w_qkv  = (const float*)d_in[1];
  const float* b_qkv  = (const float*)d_in[2];
  const float* w_dw   = (const float*)d_in[3];
  const float* b_dw   = (const float*)d_in[4];
  const float* scale  = (const float*)d_in[5];
  const float* w_proj = (const float*)d_in[6];
  const float* b_proj = (const float*)d_in[7];
  float* out = (float*)d_out;
  char* ws = (char*)d_ws;

  // per-batch workspace (reused for b=0,1), peak ~172 MB
  float* qkpre  = (float*)(ws + 0L);          // (1024,N) f32  67108864
  u16* xT_hi    = (u16*)(ws + 67108864L);     // (N,512)       16777216  -> q_hi
  u16* xT_lo    = (u16*)(ws + 83886080L);     //               16777216  -> q_lo
  u16* k_hi     = (u16*)(ws + 100663296L);    // (512,N)       16777216
  u16* k_lo     = (u16*)(ws + 117440512L);    //               16777216
  u16* vpre     = (u16*)(ws + 134217728L);    // (N,512)       16777216
  u16* vtm      = (u16*)(ws + 150994944L);    // (N,512)       16777216
  u16* whi      = (u16*)(ws + 167772160L);    // (1536,512)    1572864
  u16* wlo      = (u16*)(ws + 169345024L);    //               1572864
  float* sumsq  = (float*)(ws + 170917888L);  // 1024 f32      4096
  float* att_raw= (float*)(ws + 170921984L);  // 8*64*64 f32   131072
  float* att    = (float*)(ws + 171053056L);  //               131072
  u16* Mb       = (u16*)(ws + 171184128L);    // (512,512)     524288
  u16* q_hi = xT_hi;  // alias: xT dead after the two GEMM1 passes
  u16* q_lo = xT_lo;

  k0_cvt_w<<<dim3(768), 256, 0, stream>>>(w_qkv, whi, wlo);

  for (int b = 0; b < 2; ++b) {
    const float* xb = x + (long)b * CCH * NTOK;
    float* outb = out + (long)b * CCH * NTOK;

    hipMemsetAsync(sumsq, 0, 4096 + 131072, stream);
    k0_transpose_split<<<dim3(512, 16, 1), 256, 0, stream>>>(xb, xT_hi, xT_lo);
    // q,k channels: split GEMM -> qkpre f32 channel-major (1024, N)
    gemm_split<<<dim3(128, 8, 1), 256, 0, stream>>>(
        whi, wlo, xT_hi, xT_lo, qkpre, b_qkv, NTOK);
    // v channels: single GEMM -> vpre (N,512) token-major
    gemm_bt<u16, false><<<dim3(4, 128, 1), 256, 0, stream>>>(
        xT_hi, whi + (long)1024 * 512, vpre, b_qkv + 1024, 512);
    // depthwise q/k: channel-major strips (xT buffers reused as q output)
    k2_qk<<<dim3(4, 1024, 1), 256, 0, stream>>>(
        qkpre, w_dw, b_dw, q_hi, q_lo, k_hi, k_lo, sumsq);
    k2_v<<<dim3(16, 128, 1), 256, 0, stream>>>(vpre, w_dw, b_dw, vtm);
    // qk^T split
    k3_qk_split<<<dim3(32, 8, 1), 256, 0, stream>>>(q_hi, q_lo, k_hi, k_lo, att_raw);
    k4_sm<<<dim3(128), 256, 0, stream>>>(att_raw, sumsq, scale, att);
    k4b_m<<<dim3(8, 8, 1), 256, 0, stream>>>(att, w_proj, Mb);
    // out[c][n] = sum_d Mb[c][d] * vtm[n][d] + b_proj[c]
    gemm_bt<float, true><<<dim3(128, 4, 1), 256, 0, stream>>>(
        Mb, vtm, outb, b_proj, NTOK);
  }
}